// Round 8
// baseline (71.058 us; speedup 1.0000x reference)
//
#include <hip/hip_runtime.h>
#include <stdint.h>

// ---------------------------------------------------------------------------
// Algebraic simplification of the reference:
//   * grad / softmax / top_k results are never used (dead code).
//   * kv_sel is a broadcast -> attention softmax is uniform -> attn@v_sel = v.
//   * Net computation:
//       V = x @ W_qkv[:, 1024:1536]                      (8192x512 @ 512x512)
//       Z[bi, (pi&1)*8+hi, ni, (pi>>1)*64+d] = gelu(V[bi,pi,ni,hi*64+d])
//       Y = Z @ W_out + b_out                            (8192x512 @ 512x512)
//
// R8 model: every timed replay contains a 268-MB ws-poison fill (39.4 us,
// HBM-saturating, thrashes L2/L3). dur ~= 39.4 + (chain_bytes-31MB)/6.3TB/s.
// So: minimize chain HBM bytes. cvtx deleted (-24 MB); GEMM1 reads X fp32
// directly (gll16 into fp32 LDS, cvt at frag read — R1-proven correct) with
// BN=512 so X is fetched EXACTLY once regardless of cache state.
// ---------------------------------------------------------------------------

typedef __bf16 bf16x8 __attribute__((ext_vector_type(8)));
typedef float f32x4 __attribute__((ext_vector_type(4)));

#define HD __device__ __forceinline__

HD uint16_t f2bf(float f) {
  union { float f; uint32_t u; } v; v.f = f;
  uint32_t u = v.u;
  u += 0x7fffu + ((u >> 16) & 1u);   // RNE
  return (uint16_t)(u >> 16);
}

HD void gll16(const void* g, void* l) {
  __builtin_amdgcn_global_load_lds(
      (__attribute__((address_space(1))) void*)g,
      (__attribute__((address_space(3))) void*)l, 16, 0, 0);
}

// 8 consecutive LDS floats -> bf16x8 fragment (RNE via HW cvt).
HD bf16x8 cvt_frag(const float* p) {
  f32x4 f0 = *(const f32x4*)p;
  f32x4 f1 = *(const f32x4*)(p + 4);
  bf16x8 r;
  r[0] = (__bf16)f0[0]; r[1] = (__bf16)f0[1];
  r[2] = (__bf16)f0[2]; r[3] = (__bf16)f0[3];
  r[4] = (__bf16)f1[0]; r[5] = (__bf16)f1[1];
  r[6] = (__bf16)f1[2]; r[7] = (__bf16)f1[3];
  return r;
}

// Exact-enough GELU: erf via Abramowitz-Stegun 7.1.25 (|err|<=2.5e-5).
HD float gelu(float v) {
  float x = v * 0.70710678118654752440f;
  float ax = __builtin_fabsf(x);
  float t = __builtin_amdgcn_rcpf(1.0f + 0.47047f * ax);
  float poly = t * (0.3480242f + t * (-0.0958798f + t * 0.7478556f));
  float e = 1.0f - poly * __builtin_amdgcn_exp2f(-ax * ax * 1.44269504088896340736f);
  union { float f; uint32_t u; } ue, ux;
  ue.f = e; ux.f = x;
  ue.u = (ue.u & 0x7fffffffu) | (ux.u & 0x80000000u);
  return 0.5f * v * (1.0f + ue.f);
}

// ---------------------------------------------------------------------------
// Both weight transposes (fp32 -> bf16, out[c][k] = in[k][coloff+c]).
// ---------------------------------------------------------------------------
__global__ __launch_bounds__(256) void k_prep(
    const float* __restrict__ Wqkv, const float* __restrict__ Wout,
    uint16_t* __restrict__ WvT, uint16_t* __restrict__ WoT) {
  const float* in;
  uint16_t* out;
  int ldin, coloff;
  if (blockIdx.z == 0) { in = Wqkv; ldin = 1536; coloff = 1024; out = WvT; }
  else                 { in = Wout; ldin = 512;  coloff = 0;    out = WoT; }

  __shared__ uint16_t t[64][66];
  const int tid = threadIdx.x;
  const int tx = tid & 63;
  const int ty = tid >> 6;
  const int j0 = blockIdx.x * 64;
  const int k0 = blockIdx.y * 64;
#pragma unroll
  for (int r = 0; r < 16; ++r) {
    int k = ty * 16 + r;
    t[k][tx] = f2bf(in[(size_t)(k0 + k) * ldin + coloff + j0 + tx]);
  }
  __syncthreads();
#pragma unroll
  for (int r = 0; r < 16; ++r) {
    int j = ty * 16 + r;
    out[(size_t)(j0 + j) * 512 + k0 + tx] = t[tx][j];
  }
}

// ---------------------------------------------------------------------------
// GEMM1: Zlin = gelu(X @ Wv). BM=64, BN=512 (grid_n = 1 -> X read ONCE),
// BK=32, 256 thr / 4 waves; wave wid owns cols [wid*128, wid*128+128).
// A staged fp32 via gll16 (layout [s2][64][16] f32, linear dest), converted
// at frag-read. B bf16 [kc4][512][8]. Per stage per wave: 2 A + 8 B gll16.
// ---------------------------------------------------------------------------
__global__ __launch_bounds__(256) void k_gemm1(
    const float* __restrict__ X,       // [8192][512] fp32 (d_in)
    const uint16_t* __restrict__ WT,   // [512][512] bf16, WT[col][k]
    uint16_t* __restrict__ Zlin) {     // [8192][512] bf16, LINEAR
  __shared__ __align__(16) float As[2][2][64][16];       // 16 KB
  __shared__ __align__(16) uint16_t Bs[2][4][512][8];    // 64 KB

  const int tid = threadIdx.x;
  const int lane = tid & 63;
  const int wid = tid >> 6;
  const int tm = blockIdx.x * 64;

  f32x4 acc[4][8];
  const f32x4 zero = {0.f, 0.f, 0.f, 0.f};
#pragma unroll
  for (int i = 0; i < 4; ++i)
#pragma unroll
    for (int j = 0; j < 8; ++j) acc[i][j] = zero;

  auto stage = [&](int kk, int buf) {
    // A: wave wid loads rows [wid*16, wid*16+16); s = k-half of 16 floats.
#pragma unroll
    for (int s = 0; s < 2; ++s) {
      gll16(X + (size_t)(tm + wid * 16 + (lane >> 2)) * 512 + kk * 32 + s * 16 + (lane & 3) * 4,
            &As[buf][s][wid * 16][0]);
    }
    // B: 32 (kc, colblock) pairs over 4 waves.
#pragma unroll
    for (int s = 0; s < 8; ++s) {
      int t = wid + 4 * s;
      int kc = t & 3;
      int cb = (t >> 2) * 64;
      gll16(WT + (size_t)(cb + lane) * 512 + kk * 32 + kc * 8,
            &Bs[buf][kc][cb][0]);
    }
  };

  stage(0, 0);
  __syncthreads();

  const int lr = lane & 15;
  const int lk = lane >> 4;

  for (int kk = 0; kk < 16; ++kk) {
    const int cur = kk & 1;
    if (kk + 1 < 16) stage(kk + 1, cur ^ 1);
    bf16x8 a[4], b[8];
#pragma unroll
    for (int mi = 0; mi < 4; ++mi)
      a[mi] = cvt_frag(&As[cur][lk >> 1][mi * 16 + lr][(lk & 1) * 8]);
#pragma unroll
    for (int nj = 0; nj < 8; ++nj)
      b[nj] = *(const bf16x8*)&Bs[cur][lk][wid * 128 + nj * 16 + lr][0];
#pragma unroll
    for (int mi = 0; mi < 4; ++mi)
#pragma unroll
      for (int nj = 0; nj < 8; ++nj)
        acc[mi][nj] = __builtin_amdgcn_mfma_f32_16x16x32_bf16(
            a[mi], b[nj], acc[mi][nj], 0, 0, 0);
    __syncthreads();
  }

  // Epilogue: inline gelu + linear bf16 store.
#pragma unroll
  for (int mi = 0; mi < 4; ++mi)
#pragma unroll
    for (int nj = 0; nj < 8; ++nj)
#pragma unroll
      for (int r = 0; r < 4; ++r) {
        int m = tm + mi * 16 + lk * 4 + r;
        int j = wid * 128 + nj * 16 + lr;
        Zlin[(size_t)m * 512 + j] = f2bf(gelu(acc[mi][nj][r]));
      }
}

// ---------------------------------------------------------------------------
// GEMM2: Y = Z @ Wout + bias, fp32 out. Permutation folded into A-source
// addressing (unchanged — proven ~2.5 us).
// ---------------------------------------------------------------------------
__global__ __launch_bounds__(256) void k_gemm_bias(
    const uint16_t* __restrict__ Zlin, // [8192][512] bf16, linear V-gelu
    const uint16_t* __restrict__ WT,   // [512][512] bf16, WoT[col][k]
    const float* __restrict__ bias,    // [512]
    float* __restrict__ Y) {           // [8192][512] fp32
  __shared__ __align__(16) uint16_t As[2][4][64][8];
  __shared__ __align__(16) uint16_t Bs[2][4][128][8];

  const int tid = threadIdx.x;
  const int lane = tid & 63;
  const int wid = tid >> 6;
  const int wm = wid >> 1;
  const int wn = wid & 1;
  const int tm = blockIdx.y * 64;
  const int tn = blockIdx.x * 128;

  f32x4 acc[2][4];
  const f32x4 zero = {0.f, 0.f, 0.f, 0.f};
#pragma unroll
  for (int i = 0; i < 2; ++i)
#pragma unroll
    for (int j = 0; j < 4; ++j) acc[i][j] = zero;

  const int m2 = tm + lane;
  const int bi = m2 >> 12;
  const int pp = (m2 >> 8) & 15;
  const int ni = m2 & 255;
  const int mbase = bi * 4096 + (pp >> 3) * 256 + ni;  // + q*512 rows
  const int jbase = (pp & 7) * 64;

  auto stage = [&](int kk, int buf) {
    int k2 = kk * 32 + wid * 8;
    int q = k2 >> 6;
    int di = k2 & 63;
    gll16(Zlin + (size_t)(mbase + q * 512) * 512 + jbase + di,
          &As[buf][wid][0][0]);
#pragma unroll
    for (int s = 0; s < 2; ++s) {
      int t = wid + 4 * s;
      int kc = t >> 1;
      int cb = (t & 1) * 64;
      gll16(WT + (size_t)(tn + cb + lane) * 512 + kk * 32 + kc * 8,
            &Bs[buf][kc][cb][0]);
    }
  };

  stage(0, 0);
  __syncthreads();

  const int lr = lane & 15;
  const int lk = lane >> 4;

#pragma unroll 2
  for (int kk = 0; kk < 16; ++kk) {
    const int cur = kk & 1;
    if (kk + 1 < 16) stage(kk + 1, cur ^ 1);
    bf16x8 a[2], b[4];
#pragma unroll
    for (int mi = 0; mi < 2; ++mi)
      a[mi] = *(const bf16x8*)&As[cur][lk][wm * 32 + mi * 16 + lr][0];
#pragma unroll
    for (int nj = 0; nj < 4; ++nj)
      b[nj] = *(const bf16x8*)&Bs[cur][lk][wn * 64 + nj * 16 + lr][0];
#pragma unroll
    for (int mi = 0; mi < 2; ++mi)
#pragma unroll
      for (int nj = 0; nj < 4; ++nj)
        acc[mi][nj] = __builtin_amdgcn_mfma_f32_16x16x32_bf16(
            a[mi], b[nj], acc[mi][nj], 0, 0, 0);
    __syncthreads();
  }

#pragma unroll
  for (int mi = 0; mi < 2; ++mi)
#pragma unroll
    for (int nj = 0; nj < 4; ++nj) {
      int j = tn + wn * 64 + nj * 16 + lr;
      float bj = bias[j];
#pragma unroll
      for (int r = 0; r < 4; ++r) {
        int m = tm + wm * 32 + mi * 16 + lk * 4 + r;
        Y[(size_t)m * 512 + j] = acc[mi][nj][r] + bj;
      }
    }
}

// ---------------------------------------------------------------------------
extern "C" void kernel_launch(void* const* d_in, const int* in_sizes, int n_in,
                              void* d_out, int out_size, void* d_ws, size_t ws_size,
                              hipStream_t stream) {
  const float* x    = (const float*)d_in[0];
  // d_in[1] = grad : provably unused by the reference's dataflow.
  const float* Wqkv = (const float*)d_in[2];   // [512][1536]
  const float* Wout = (const float*)d_in[3];   // [512][512]
  const float* bout = (const float*)d_in[4];   // [512]
  float* Y = (float*)d_out;

  uint16_t* WvT = (uint16_t*)d_ws;             // 512*512 bf16 (0.5 MB)
  uint16_t* WoT = WvT + 512 * 512;             // 0.5 MB
  uint16_t* Z   = WoT + 512 * 512;             // 8192*512 bf16 (8 MB)

  dim3 tb(256);
  k_prep<<<dim3(8, 8, 2), tb, 0, stream>>>(Wqkv, Wout, WvT, WoT);
  k_gemm1<<<dim3(128), tb, 0, stream>>>(x, WvT, Z);
  k_gemm_bias<<<dim3(4, 128), tb, 0, stream>>>(Z, WoT, bout, Y);
}

// Round 9
// 57.524 us; speedup vs baseline: 1.2353x; 1.2353x over previous
//
#include <hip/hip_runtime.h>
#include <stdint.h>

// ---------------------------------------------------------------------------
// Algebraic simplification of the reference:
//   * grad / softmax / top_k results are never used (dead code).
//   * kv_sel is a broadcast -> attention softmax is uniform -> attn@v_sel = v.
//   * Net computation:
//       V = x @ W_qkv[:, 1024:1536]                      (8192x512 @ 512x512)
//       Z[bi, (pi&1)*8+hi, ni, (pi>>1)*64+d] = gelu(V[bi,pi,ni,hi*64+d])
//       Y = Z @ W_out + b_out                            (8192x512 @ 512x512)
//
// R9 model (from 9 rounds of elimination): shader reads of d_in run at only
// ~0.4-1 TB/s regardless of kernel structure/TLP (fine-grained / L3-bypass
// allocation signature). Every round's hidden ~40 us was the d_in->shader
// read path (gemm1 in R0-R2, cvtx since R3). Fix: pull ALL d_in bytes into
// d_ws via SDMA (hipMemcpyAsync D2D — explicitly harness-allowed), which
// doesn't use the shader uncached path; all kernels then read cached ws.
// ---------------------------------------------------------------------------

typedef __bf16 bf16x8 __attribute__((ext_vector_type(8)));
typedef float f32x4 __attribute__((ext_vector_type(4)));
typedef unsigned short u16x8 __attribute__((ext_vector_type(8)));

#define HD __device__ __forceinline__

HD uint16_t f2bf(float f) {
  union { float f; uint32_t u; } v; v.f = f;
  uint32_t u = v.u;
  u += 0x7fffu + ((u >> 16) & 1u);   // RNE
  return (uint16_t)(u >> 16);
}

HD void gll16(const void* g, void* l) {
  __builtin_amdgcn_global_load_lds(
      (__attribute__((address_space(1))) void*)g,
      (__attribute__((address_space(3))) void*)l, 16, 0, 0);
}

// Exact-enough GELU: erf via Abramowitz-Stegun 7.1.25 (|err|<=2.5e-5).
HD float gelu(float v) {
  float x = v * 0.70710678118654752440f;
  float ax = __builtin_fabsf(x);
  float t = __builtin_amdgcn_rcpf(1.0f + 0.47047f * ax);
  float poly = t * (0.3480242f + t * (-0.0958798f + t * 0.7478556f));
  float e = 1.0f - poly * __builtin_amdgcn_exp2f(-ax * ax * 1.44269504088896340736f);
  union { float f; uint32_t u; } ue, ux;
  ue.f = e; ux.f = x;
  ue.u = (ue.u & 0x7fffffffu) | (ux.u & 0x80000000u);
  return 0.5f * v * (1.0f + ue.f);
}

// ---------------------------------------------------------------------------
// X fp32 (ws copy) -> bf16. 8 elem/thread, 2048 blocks (exact cover).
// ---------------------------------------------------------------------------
__global__ __launch_bounds__(256) void k_cvtx(
    const float* __restrict__ X, uint16_t* __restrict__ Xb) {
  const size_t i = ((size_t)blockIdx.x * 256 + threadIdx.x) * 8;
  f32x4 a = *(const f32x4*)(X + i);
  f32x4 b = *(const f32x4*)(X + i + 4);
  u16x8 o;
  o[0] = f2bf(a[0]); o[1] = f2bf(a[1]); o[2] = f2bf(a[2]); o[3] = f2bf(a[3]);
  o[4] = f2bf(b[0]); o[5] = f2bf(b[1]); o[6] = f2bf(b[2]); o[7] = f2bf(b[3]);
  *(u16x8*)(Xb + i) = o;
}

// ---------------------------------------------------------------------------
// Weight transpose from ws copies (both now [512][512] fp32, coloff=0):
// out[c][k] = bf16(in[k][c]). 64x64 tiles; z selects {Wv, Wout}.
// ---------------------------------------------------------------------------
__global__ __launch_bounds__(256) void k_prep(
    const float* __restrict__ Wvf, const float* __restrict__ Wof,
    uint16_t* __restrict__ WvT, uint16_t* __restrict__ WoT) {
  const float* in = (blockIdx.z == 0) ? Wvf : Wof;
  uint16_t* out   = (blockIdx.z == 0) ? WvT : WoT;

  __shared__ uint16_t t[64][66];
  const int tid = threadIdx.x;
  const int tx = tid & 63;
  const int ty = tid >> 6;
  const int j0 = blockIdx.x * 64;
  const int k0 = blockIdx.y * 64;
#pragma unroll
  for (int r = 0; r < 16; ++r) {
    int k = ty * 16 + r;
    t[k][tx] = f2bf(in[(size_t)(k0 + k) * 512 + j0 + tx]);
  }
  __syncthreads();
#pragma unroll
  for (int r = 0; r < 16; ++r) {
    int j = ty * 16 + r;
    out[(size_t)(j0 + j) * 512 + k0 + tx] = t[tx][j];
  }
}

// ---------------------------------------------------------------------------
// GEMM1: Zlin = gelu(Xb @ Wv), linear bf16 store.
// BM=64 BN=128 BK=32, 256 thr (4 waves, each 32x64 = 2x4 frags of 16x16).
// Proven-fast structure (identical to k_gemm_bias's ~2.5us body).
// ---------------------------------------------------------------------------
__global__ __launch_bounds__(256) void k_gemm1(
    const uint16_t* __restrict__ Xb,   // [8192][512] bf16 (ws)
    const uint16_t* __restrict__ WT,   // [512][512] bf16, WT[col][k] (ws)
    uint16_t* __restrict__ Zlin) {     // [8192][512] bf16, LINEAR (ws)
  __shared__ __align__(16) uint16_t As[2][4][64][8];
  __shared__ __align__(16) uint16_t Bs[2][4][128][8];

  const int tid = threadIdx.x;
  const int lane = tid & 63;
  const int wid = tid >> 6;
  const int wm = wid >> 1;
  const int wn = wid & 1;
  const int tm = blockIdx.y * 64;
  const int tn = blockIdx.x * 128;

  f32x4 acc[2][4];
  const f32x4 zero = {0.f, 0.f, 0.f, 0.f};
#pragma unroll
  for (int i = 0; i < 2; ++i)
#pragma unroll
    for (int j = 0; j < 4; ++j) acc[i][j] = zero;

  auto stage = [&](int kk, int buf) {
    gll16(Xb + (size_t)(tm + lane) * 512 + kk * 32 + wid * 8,
          &As[buf][wid][0][0]);
#pragma unroll
    for (int s = 0; s < 2; ++s) {
      int t = wid + 4 * s;
      int kc = t >> 1;
      int cb = (t & 1) * 64;
      gll16(WT + (size_t)(tn + cb + lane) * 512 + kk * 32 + kc * 8,
            &Bs[buf][kc][cb][0]);
    }
  };

  stage(0, 0);
  __syncthreads();

  const int lr = lane & 15;
  const int lk = lane >> 4;

#pragma unroll 2
  for (int kk = 0; kk < 16; ++kk) {
    const int cur = kk & 1;
    if (kk + 1 < 16) stage(kk + 1, cur ^ 1);
    bf16x8 a[2], b[4];
#pragma unroll
    for (int mi = 0; mi < 2; ++mi)
      a[mi] = *(const bf16x8*)&As[cur][lk][wm * 32 + mi * 16 + lr][0];
#pragma unroll
    for (int nj = 0; nj < 4; ++nj)
      b[nj] = *(const bf16x8*)&Bs[cur][lk][wn * 64 + nj * 16 + lr][0];
#pragma unroll
    for (int mi = 0; mi < 2; ++mi)
#pragma unroll
      for (int nj = 0; nj < 4; ++nj)
        acc[mi][nj] = __builtin_amdgcn_mfma_f32_16x16x32_bf16(
            a[mi], b[nj], acc[mi][nj], 0, 0, 0);
    __syncthreads();
  }

#pragma unroll
  for (int mi = 0; mi < 2; ++mi)
#pragma unroll
    for (int nj = 0; nj < 4; ++nj)
#pragma unroll
      for (int r = 0; r < 4; ++r) {
        int m = tm + wm * 32 + mi * 16 + lk * 4 + r;
        int j = tn + wn * 64 + nj * 16 + lr;
        Zlin[(size_t)m * 512 + j] = f2bf(gelu(acc[mi][nj][r]));
      }
}

// ---------------------------------------------------------------------------
// GEMM2: Y = Z @ Wout + bias, fp32 out. Permutation folded into A-source
// addressing:  A[m2][k2] = Zlin[m][j], m2=(bi,pp,ni), k2=(q,di):
//   pi=2q+(pp>>3), hi=pp&7, m=bi*4096+pi*256+ni, j=hi*64+di.
// ---------------------------------------------------------------------------
__global__ __launch_bounds__(256) void k_gemm_bias(
    const uint16_t* __restrict__ Zlin, // [8192][512] bf16 (ws)
    const uint16_t* __restrict__ WT,   // [512][512] bf16 (ws)
    const float* __restrict__ bias,    // [512] (d_in; 2KB, negligible)
    float* __restrict__ Y) {           // [8192][512] fp32 (d_out)
  __shared__ __align__(16) uint16_t As[2][4][64][8];
  __shared__ __align__(16) uint16_t Bs[2][4][128][8];

  const int tid = threadIdx.x;
  const int lane = tid & 63;
  const int wid = tid >> 6;
  const int wm = wid >> 1;
  const int wn = wid & 1;
  const int tm = blockIdx.y * 64;
  const int tn = blockIdx.x * 128;

  f32x4 acc[2][4];
  const f32x4 zero = {0.f, 0.f, 0.f, 0.f};
#pragma unroll
  for (int i = 0; i < 2; ++i)
#pragma unroll
    for (int j = 0; j < 4; ++j) acc[i][j] = zero;

  const int m2 = tm + lane;
  const int bi = m2 >> 12;
  const int pp = (m2 >> 8) & 15;
  const int ni = m2 & 255;
  const int mbase = bi * 4096 + (pp >> 3) * 256 + ni;  // + q*512 rows
  const int jbase = (pp & 7) * 64;

  auto stage = [&](int kk, int buf) {
    int k2 = kk * 32 + wid * 8;
    int q = k2 >> 6;
    int di = k2 & 63;
    gll16(Zlin + (size_t)(mbase + q * 512) * 512 + jbase + di,
          &As[buf][wid][0][0]);
#pragma unroll
    for (int s = 0; s < 2; ++s) {
      int t = wid + 4 * s;
      int kc = t >> 1;
      int cb = (t & 1) * 64;
      gll16(WT + (size_t)(tn + cb + lane) * 512 + kk * 32 + kc * 8,
            &Bs[buf][kc][cb][0]);
    }
  };

  stage(0, 0);
  __syncthreads();

  const int lr = lane & 15;
  const int lk = lane >> 4;

#pragma unroll 2
  for (int kk = 0; kk < 16; ++kk) {
    const int cur = kk & 1;
    if (kk + 1 < 16) stage(kk + 1, cur ^ 1);
    bf16x8 a[2], b[4];
#pragma unroll
    for (int mi = 0; mi < 2; ++mi)
      a[mi] = *(const bf16x8*)&As[cur][lk][wm * 32 + mi * 16 + lr][0];
#pragma unroll
    for (int nj = 0; nj < 4; ++nj)
      b[nj] = *(const bf16x8*)&Bs[cur][lk][wn * 64 + nj * 16 + lr][0];
#pragma unroll
    for (int mi = 0; mi < 2; ++mi)
#pragma unroll
      for (int nj = 0; nj < 4; ++nj)
        acc[mi][nj] = __builtin_amdgcn_mfma_f32_16x16x32_bf16(
            a[mi], b[nj], acc[mi][nj], 0, 0, 0);
    __syncthreads();
  }

#pragma unroll
  for (int mi = 0; mi < 2; ++mi)
#pragma unroll
    for (int nj = 0; nj < 4; ++nj) {
      int j = tn + wn * 64 + nj * 16 + lr;
      float bj = bias[j];
#pragma unroll
      for (int r = 0; r < 4; ++r) {
        int m = tm + wm * 32 + mi * 16 + lk * 4 + r;
        Y[(size_t)m * 512 + j] = acc[mi][nj][r] + bj;
      }
    }
}

// ---------------------------------------------------------------------------
extern "C" void kernel_launch(void* const* d_in, const int* in_sizes, int n_in,
                              void* d_out, int out_size, void* d_ws, size_t ws_size,
                              hipStream_t stream) {
  const float* x    = (const float*)d_in[0];
  // d_in[1] = grad : provably unused by the reference's dataflow.
  const float* Wqkv = (const float*)d_in[2];   // [512][1536]
  const float* Wout = (const float*)d_in[3];   // [512][512]
  const float* bout = (const float*)d_in[4];   // [512]
  float* Y = (float*)d_out;

  // ws layout (36 MB of ~256 MB):
  uint16_t* WvT = (uint16_t*)d_ws;                   // 0.5 MB bf16 WvT[c][k]
  uint16_t* WoT = WvT + 512 * 512;                   // 0.5 MB
  uint16_t* Z   = WoT + 512 * 512;                   // 8 MB  bf16
  uint16_t* Xb  = Z + 8192 * 512;                    // 8 MB  bf16
  float*    Xf  = (float*)(Xb + 8192 * 512);         // 16 MB fp32 (X copy)
  float*    Wvf = Xf + 8192 * 512;                   // 1 MB  fp32 (V-slice)
  float*    Wof = Wvf + 512 * 512;                   // 1 MB  fp32 (Wout copy)

  // SDMA pulls of all needed d_in bytes (shader-uncached path avoided).
  hipMemcpyAsync(Xf, x, (size_t)8192 * 512 * 4, hipMemcpyDeviceToDevice, stream);
  hipMemcpy2DAsync(Wvf, 512 * 4, Wqkv + 1024, 1536 * 4, 512 * 4, 512,
                   hipMemcpyDeviceToDevice, stream);
  hipMemcpyAsync(Wof, Wout, (size_t)512 * 512 * 4, hipMemcpyDeviceToDevice, stream);

  dim3 tb(256);
  k_cvtx<<<dim3(2048), tb, 0, stream>>>(Xf, Xb);
  k_prep<<<dim3(8, 8, 2), tb, 0, stream>>>(Wvf, Wof, WvT, WoT);
  k_gemm1<<<dim3(4, 128), tb, 0, stream>>>(Xb, WvT, Z);
  k_gemm_bias<<<dim3(4, 128), tb, 0, stream>>>(Z, WoT, bout, Y);
}